// Round 19
// baseline (4910.798 us; speedup 1.0000x reference)
//
#include <hip/hip_runtime.h>
#include <hip/hip_fp16.h>

#define T_LEN 8192
#define N_NODES 33
#define N_EDGES 64
#define DIM_IN 3
#define D_H 64
#define D_LSTM 128
#define N_CLS 5
#define TB 4   // timesteps per block in kernel 1

typedef float v2f __attribute__((ext_vector_type(2)));
typedef float v4f __attribute__((ext_vector_type(4)));

// ---------------------------------------------------------------------------
// Kernel 1: graph conv x2 + relu + mean over nodes + input-side LSTM projection
// Writes A in (T, 128, 4) layout: A[(t*128+q)*4 + g] = gate g of unit q
// (g: 0=i, 1=f, 2=g, 3=o).  LSTM lane loads its unit's 4 gates as one dwordx4.
// ---------------------------------------------------------------------------
__global__ __launch_bounds__(64, 2) void gnn_proj_kernel(
    const float* __restrict__ x,        // (T,33,3)
    const int*   __restrict__ esrc,     // (64,)
    const int*   __restrict__ edst,     // (64,)
    const float* __restrict__ W_rel1,   // (64,3)
    const float* __restrict__ b_rel1,   // (64,)
    const float* __restrict__ W_root1,  // (64,3)
    const float* __restrict__ W_rel2,   // (64,64)
    const float* __restrict__ b_rel2,   // (64,)
    const float* __restrict__ W_root2,  // (64,64)
    const float* __restrict__ W_ih,     // (512,64)
    const float* __restrict__ b_ih,     // (512,)
    const float* __restrict__ b_hh,     // (512,)
    float* __restrict__ A)              // (T,128,4)  [workspace]
{
    const int t0 = blockIdx.x * TB;
    const int j  = threadIdx.x;   // 0..63

    __shared__ __align__(16) float x_s[N_NODES][DIM_IN];
    __shared__ __align__(16) float agg1[N_NODES][DIM_IN];
    __shared__ __align__(16) float h1[N_NODES][D_H];
    __shared__ __align__(16) float agg2[N_NODES][D_H];
    __shared__ __align__(16) float seq_s[TB][D_H];
    __shared__ int es[N_EDGES], ed[N_EDGES];

    es[j] = esrc[j];
    ed[j] = edst[j];

    const float wr1_0 = W_rel1[j*3+0], wr1_1 = W_rel1[j*3+1], wr1_2 = W_rel1[j*3+2];
    const float wt1_0 = W_root1[j*3+0], wt1_1 = W_root1[j*3+1], wt1_2 = W_root1[j*3+2];
    const float br1 = b_rel1[j];
    const float br2 = b_rel2[j];

    float wr2[D_H], wt2[D_H];
    #pragma unroll
    for (int k = 0; k < D_H; ++k) {
        wr2[k] = W_rel2[j*D_H + k];
        wt2[k] = W_root2[j*D_H + k];
    }

    for (int tt = 0; tt < TB; ++tt) {
        const int t = t0 + tt;
        __syncthreads();

        const float* xt = x + (size_t)t * (N_NODES * DIM_IN);
        for (int i = j; i < N_NODES * DIM_IN; i += 64) x_s[0][i] = xt[i];
        __syncthreads();

        if (j < N_NODES) {
            float a0 = 0.f, a1 = 0.f, a2 = 0.f;
            for (int e = 0; e < N_EDGES; ++e) {
                if (ed[e] == j) {
                    a0 += x_s[es[e]][0];
                    a1 += x_s[es[e]][1];
                    a2 += x_s[es[e]][2];
                }
            }
            agg1[j][0] = a0; agg1[j][1] = a1; agg1[j][2] = a2;
        }
        __syncthreads();

        for (int n = 0; n < N_NODES; ++n) {
            float v = br1
                + agg1[n][0]*wr1_0 + agg1[n][1]*wr1_1 + agg1[n][2]*wr1_2
                + x_s[n][0]*wt1_0  + x_s[n][1]*wt1_1  + x_s[n][2]*wt1_2;
            h1[n][j]  = v;
            agg2[n][j] = 0.f;
        }
        __syncthreads();

        for (int e = 0; e < N_EDGES; ++e) {
            agg2[ed[e]][j] += h1[es[e]][j];
        }
        __syncthreads();

        float seqv = 0.f;
        for (int n = 0; n < N_NODES; ++n) {
            const float4* ag4 = (const float4*)agg2[n];
            const float4* h4  = (const float4*)h1[n];
            float acc0 = br2, acc1 = 0.f, acc2 = 0.f, acc3 = 0.f;
            #pragma unroll
            for (int k4 = 0; k4 < D_H/4; ++k4) {
                float4 av = ag4[k4];
                float4 hv = h4[k4];
                acc0 += av.x * wr2[4*k4+0] + hv.x * wt2[4*k4+0];
                acc1 += av.y * wr2[4*k4+1] + hv.y * wt2[4*k4+1];
                acc2 += av.z * wr2[4*k4+2] + hv.z * wt2[4*k4+2];
                acc3 += av.w * wr2[4*k4+3] + hv.w * wt2[4*k4+3];
            }
            float acc = (acc0 + acc1) + (acc2 + acc3);
            seqv += fmaxf(acc, 0.f);
        }
        seq_s[tt][j] = seqv * (1.0f / 33.0f);
    }
    __syncthreads();

    #pragma unroll
    for (int m = 0; m < 8; ++m) {
        const int o = m * 64 + j;
        const float bias = b_ih[o] + b_hh[o];
        const float4* w4 = (const float4*)(W_ih + (size_t)o * D_H);
        float acc[TB];
        #pragma unroll
        for (int tt = 0; tt < TB; ++tt) acc[tt] = bias;
        #pragma unroll
        for (int k4 = 0; k4 < D_H/4; ++k4) {
            float4 wv = w4[k4];
            #pragma unroll
            for (int tt = 0; tt < TB; ++tt) {
                const float4* s4 = (const float4*)seq_s[tt];
                float4 sv = s4[k4];
                acc[tt] += sv.x*wv.x + sv.y*wv.y + sv.z*wv.z + sv.w*wv.w;
            }
        }
        // (T,128,4) layout: q = o&127, g = o>>7
        #pragma unroll
        for (int tt = 0; tt < TB; ++tt) {
            A[((size_t)(t0 + tt) * 128 + (o & 127)) * 4 + (o >> 7)] = acc[tt];
        }
    }
}

// ---------------------------------------------------------------------------
// Kernel 2 (round 19): MFMA LSTM, 256 threads = 4 waves, 1 wave/SIMD.
// r18 (8 waves, 2/SIMD) measured 1034 cyc/step with ~380 cyc of VALU issue
// contention (two barrier-locked waves serializing identical nonlin blocks).
// Now wave w owns 32 units (q0=32w): 8 gate-tiles x 4 K-chunks = 32 mfma
// (dep distance 8), weights = 128 VGPRs v0-127.  Each lane finishes TWO
// units: u1 = q0+4*(l>>4)+(l&3) (tile A), u2 = u1+16 (tile B); nonlin = two
// interleaved r11-proven chains.  Weight addr = SGPR base + computed voffset
// (keeps asm VGPR operands <= 4).  A-prefetch 2x dwordx4/step, vmcnt(2).
// Regs: v0-127 W | v128-143 B | v144-175 D (+prologue staging) | v176-191 A
// dbuf | v200-203 zeros | v204-231 temps | v228/229 c1,c2 | v232 addr.
// ---------------------------------------------------------------------------

#define CVTPK(D,S0,S1) \
  "v_cvt_f16_f32 v204, v" #S0 "\n\t" \
  "v_cvt_f16_f32 v205, v" #S1 "\n\t" \
  "v_and_b32 v204, 0xffff, v204\n\t" \
  "v_lshlrev_b32 v205, 16, v205\n\t" \
  "v_or_b32 v" #D ", v204, v205\n\t"

#define ROWPACK(D0,D1,D2,D3,D4,D5,D6,D7,D8,D9,D10,D11,D12,D13,D14,D15) \
  CVTPK(D0,144,145) CVTPK(D1,146,147) CVTPK(D2,148,149) CVTPK(D3,150,151) \
  CVTPK(D4,152,153) CVTPK(D5,154,155) CVTPK(D6,156,157) CVTPK(D7,158,159) \
  CVTPK(D8,160,161) CVTPK(D9,162,163) CVTPK(D10,164,165) CVTPK(D11,166,167) \
  CVTPK(D12,168,169) CVTPK(D13,170,171) CVTPK(D14,172,173) CVTPK(D15,174,175)

// stage one 16-row tile (8 f32 / lane / K-chunk, chunks at bytes kt*128)
#define FRAGLOAD(VOFF) \
  "global_load_dwordx4 v[144:147], " VOFF ", %[whh]\n\t" \
  "global_load_dwordx4 v[148:151], " VOFF ", %[whh] offset:16\n\t" \
  "global_load_dwordx4 v[152:155], " VOFF ", %[whh] offset:128\n\t" \
  "global_load_dwordx4 v[156:159], " VOFF ", %[whh] offset:144\n\t" \
  "global_load_dwordx4 v[160:163], " VOFF ", %[whh] offset:256\n\t" \
  "global_load_dwordx4 v[164:167], " VOFF ", %[whh] offset:272\n\t" \
  "global_load_dwordx4 v[168:171], " VOFF ", %[whh] offset:384\n\t" \
  "global_load_dwordx4 v[172:175], " VOFF ", %[whh] offset:400\n\t" \
  "s_waitcnt vmcnt(0)\n\t"

// one LSTM step. P* = prefetch dest regs, PC* = consume regs (A biases),
// R* = h read offsets, W1/W2 = h write offsets (u1 / u2)
#define HALF(P0,P3,P4,P7, PC0,PC1,PC2,PC3,PC4,PC5,PC6,PC7, R0,R1,R2,R3, W1,W2) \
  "ds_read_b128 v[128:131], %[rb] offset:" #R0 "\n\t" \
  "ds_read_b128 v[132:135], %[rb] offset:" #R1 "\n\t" \
  "ds_read_b128 v[136:139], %[rb] offset:" #R2 "\n\t" \
  "ds_read_b128 v[140:143], %[rb] offset:" #R3 "\n\t" \
  "v_add_u32 v232, s80, %[at]\n\t" \
  "global_load_dwordx4 v[" #P0 ":" #P3 "], v232, %[ab]\n\t" \
  "global_load_dwordx4 v[" #P4 ":" #P7 "], v232, %[ab] offset:256\n\t" \
  "s_add_u32 s80, s80, 2048\n\t" \
  "s_cmp_lg_u32 s80, 0x1000000\n\t" \
  "s_cselect_b32 s80, s80, 0\n\t" \
  "s_waitcnt lgkmcnt(0)\n\t" \
  /* 32 mfma: 8 chains (iA fA gA oA iB fB gB oB) x 4 K-chunks */ \
  "v_mfma_f32_16x16x32_f16 v[144:147], v[0:3],     v[128:131], v[200:203]\n\t" \
  "v_mfma_f32_16x16x32_f16 v[148:151], v[16:19],   v[128:131], v[200:203]\n\t" \
  "v_mfma_f32_16x16x32_f16 v[152:155], v[32:35],   v[128:131], v[200:203]\n\t" \
  "v_mfma_f32_16x16x32_f16 v[156:159], v[48:51],   v[128:131], v[200:203]\n\t" \
  "v_mfma_f32_16x16x32_f16 v[160:163], v[64:67],   v[128:131], v[200:203]\n\t" \
  "v_mfma_f32_16x16x32_f16 v[164:167], v[80:83],   v[128:131], v[200:203]\n\t" \
  "v_mfma_f32_16x16x32_f16 v[168:171], v[96:99],   v[128:131], v[200:203]\n\t" \
  "v_mfma_f32_16x16x32_f16 v[172:175], v[112:115], v[128:131], v[200:203]\n\t" \
  "v_mfma_f32_16x16x32_f16 v[144:147], v[4:7],     v[132:135], v[144:147]\n\t" \
  "v_mfma_f32_16x16x32_f16 v[148:151], v[20:23],   v[132:135], v[148:151]\n\t" \
  "v_mfma_f32_16x16x32_f16 v[152:155], v[36:39],   v[132:135], v[152:155]\n\t" \
  "v_mfma_f32_16x16x32_f16 v[156:159], v[52:55],   v[132:135], v[156:159]\n\t" \
  "v_mfma_f32_16x16x32_f16 v[160:163], v[68:71],   v[132:135], v[160:163]\n\t" \
  "v_mfma_f32_16x16x32_f16 v[164:167], v[84:87],   v[132:135], v[164:167]\n\t" \
  "v_mfma_f32_16x16x32_f16 v[168:171], v[100:103], v[132:135], v[168:171]\n\t" \
  "v_mfma_f32_16x16x32_f16 v[172:175], v[116:119], v[132:135], v[172:175]\n\t" \
  "v_mfma_f32_16x16x32_f16 v[144:147], v[8:11],    v[136:139], v[144:147]\n\t" \
  "v_mfma_f32_16x16x32_f16 v[148:151], v[24:27],   v[136:139], v[148:151]\n\t" \
  "v_mfma_f32_16x16x32_f16 v[152:155], v[40:43],   v[136:139], v[152:155]\n\t" \
  "v_mfma_f32_16x16x32_f16 v[156:159], v[56:59],   v[136:139], v[156:159]\n\t" \
  "v_mfma_f32_16x16x32_f16 v[160:163], v[72:75],   v[136:139], v[160:163]\n\t" \
  "v_mfma_f32_16x16x32_f16 v[164:167], v[88:91],   v[136:139], v[164:167]\n\t" \
  "v_mfma_f32_16x16x32_f16 v[168:171], v[104:107], v[136:139], v[168:171]\n\t" \
  "v_mfma_f32_16x16x32_f16 v[172:175], v[120:123], v[136:139], v[172:175]\n\t" \
  "v_mfma_f32_16x16x32_f16 v[144:147], v[12:15],   v[140:143], v[144:147]\n\t" \
  "v_mfma_f32_16x16x32_f16 v[148:151], v[28:31],   v[140:143], v[148:151]\n\t" \
  "v_mfma_f32_16x16x32_f16 v[152:155], v[44:47],   v[140:143], v[152:155]\n\t" \
  "v_mfma_f32_16x16x32_f16 v[156:159], v[60:63],   v[140:143], v[156:159]\n\t" \
  "v_mfma_f32_16x16x32_f16 v[160:163], v[76:79],   v[140:143], v[160:163]\n\t" \
  "v_mfma_f32_16x16x32_f16 v[164:167], v[92:95],   v[140:143], v[164:167]\n\t" \
  "v_mfma_f32_16x16x32_f16 v[168:171], v[108:111], v[140:143], v[168:171]\n\t" \
  "v_mfma_f32_16x16x32_f16 v[172:175], v[124:127], v[140:143], v[172:175]\n\t" \
  "s_nop 7\n\t" \
  "s_nop 7\n\t" \
  /* selects: r = lane&3 per gate-tile -> unit1 gates v208-211, unit2 v212-215 */ \
  "v_cndmask_b32 v204, v144, v146, %[sb1]\n\t" \
  "v_cndmask_b32 v205, v145, v147, %[sb1]\n\t" \
  "v_cndmask_b32 v208, v204, v205, %[sb0]\n\t" \
  "v_cndmask_b32 v204, v148, v150, %[sb1]\n\t" \
  "v_cndmask_b32 v205, v149, v151, %[sb1]\n\t" \
  "v_cndmask_b32 v209, v204, v205, %[sb0]\n\t" \
  "v_cndmask_b32 v204, v152, v154, %[sb1]\n\t" \
  "v_cndmask_b32 v205, v153, v155, %[sb1]\n\t" \
  "v_cndmask_b32 v210, v204, v205, %[sb0]\n\t" \
  "v_cndmask_b32 v204, v156, v158, %[sb1]\n\t" \
  "v_cndmask_b32 v205, v157, v159, %[sb1]\n\t" \
  "v_cndmask_b32 v211, v204, v205, %[sb0]\n\t" \
  "v_cndmask_b32 v204, v160, v162, %[sb1]\n\t" \
  "v_cndmask_b32 v205, v161, v163, %[sb1]\n\t" \
  "v_cndmask_b32 v212, v204, v205, %[sb0]\n\t" \
  "v_cndmask_b32 v204, v164, v166, %[sb1]\n\t" \
  "v_cndmask_b32 v205, v165, v167, %[sb1]\n\t" \
  "v_cndmask_b32 v213, v204, v205, %[sb0]\n\t" \
  "v_cndmask_b32 v204, v168, v170, %[sb1]\n\t" \
  "v_cndmask_b32 v205, v169, v171, %[sb1]\n\t" \
  "v_cndmask_b32 v214, v204, v205, %[sb0]\n\t" \
  "v_cndmask_b32 v204, v172, v174, %[sb1]\n\t" \
  "v_cndmask_b32 v205, v173, v175, %[sb1]\n\t" \
  "v_cndmask_b32 v215, v204, v205, %[sb0]\n\t" \
  /* + A biases */ \
  "s_waitcnt vmcnt(2)\n\t" \
  "v_add_f32 v208, v208, v" #PC0 "\n\t" \
  "v_add_f32 v209, v209, v" #PC1 "\n\t" \
  "v_add_f32 v210, v210, v" #PC2 "\n\t" \
  "v_add_f32 v211, v211, v" #PC3 "\n\t" \
  "v_add_f32 v212, v212, v" #PC4 "\n\t" \
  "v_add_f32 v213, v213, v" #PC5 "\n\t" \
  "v_add_f32 v214, v214, v" #PC6 "\n\t" \
  "v_add_f32 v215, v215, v" #PC7 "\n\t" \
  /* nonlin x2 units, interleaved (trans gaps >= 5) */ \
  "v_mul_f32 v216, s87, v208\n\t" \
  "v_mul_f32 v217, s87, v209\n\t" \
  "v_mul_f32 v218, s88, v210\n\t" \
  "v_mul_f32 v219, s87, v211\n\t" \
  "v_mul_f32 v220, s87, v212\n\t" \
  "v_mul_f32 v221, s87, v213\n\t" \
  "v_mul_f32 v222, s88, v214\n\t" \
  "v_mul_f32 v223, s87, v215\n\t" \
  "v_exp_f32 v216, v216\n\t" \
  "v_exp_f32 v217, v217\n\t" \
  "v_exp_f32 v218, v218\n\t" \
  "v_exp_f32 v219, v219\n\t" \
  "v_exp_f32 v220, v220\n\t" \
  "v_exp_f32 v221, v221\n\t" \
  "v_exp_f32 v222, v222\n\t" \
  "v_exp_f32 v223, v223\n\t" \
  "v_add_f32 v216, 1.0, v216\n\t" \
  "v_add_f32 v217, 1.0, v217\n\t" \
  "v_add_f32 v218, 1.0, v218\n\t" \
  "v_add_f32 v219, 1.0, v219\n\t" \
  "v_add_f32 v220, 1.0, v220\n\t" \
  "v_add_f32 v221, 1.0, v221\n\t" \
  "v_add_f32 v222, 1.0, v222\n\t" \
  "v_add_f32 v223, 1.0, v223\n\t" \
  "v_rcp_f32 v218, v218\n\t" \
  "v_rcp_f32 v222, v222\n\t" \
  "v_rcp_f32 v216, v216\n\t" \
  "v_rcp_f32 v217, v217\n\t" \
  "v_rcp_f32 v219, v219\n\t" \
  "v_rcp_f32 v220, v220\n\t" \
  "v_rcp_f32 v221, v221\n\t" \
  "v_rcp_f32 v223, v223\n\t" \
  "v_fma_f32 v218, v218, 2.0, -1.0\n\t" \
  "v_fma_f32 v222, v222, 2.0, -1.0\n\t" \
  "v_mul_f32 v224, v216, v218\n\t" \
  "v_mul_f32 v225, v220, v222\n\t" \
  "v_fma_f32 v228, v217, v228, v224\n\t" \
  "v_fma_f32 v229, v221, v229, v225\n\t" \
  "v_mul_f32 v226, s88, v228\n\t" \
  "v_mul_f32 v227, s88, v229\n\t" \
  "v_exp_f32 v226, v226\n\t" \
  "v_exp_f32 v227, v227\n\t" \
  "s_nop 1\n\t" \
  "v_add_f32 v226, 1.0, v226\n\t" \
  "v_add_f32 v227, 1.0, v227\n\t" \
  "v_rcp_f32 v226, v226\n\t" \
  "v_rcp_f32 v227, v227\n\t" \
  "s_nop 1\n\t" \
  "v_fma_f32 v226, v226, 2.0, -1.0\n\t" \
  "v_fma_f32 v227, v227, 2.0, -1.0\n\t" \
  "v_mul_f32 v230, v219, v226\n\t" \
  "v_mul_f32 v231, v223, v227\n\t" \
  "v_cvt_f16_f32 v230, v230\n\t" \
  "v_cvt_f16_f32 v231, v231\n\t" \
  /* write h f16 for u1,u2 (16 writer lanes) */ \
  "s_and_saveexec_b64 s[84:85], s[82:83]\n\t" \
  "ds_write_b16 %[wr], v230 offset:" #W1 "\n\t" \
  "ds_write_b16 %[wr], v231 offset:" #W2 "\n\t" \
  "s_mov_b64 exec, s[84:85]\n\t" \
  "s_waitcnt lgkmcnt(0)\n\t" \
  "s_barrier\n\t"

__global__ __launch_bounds__(256, 1)
__attribute__((amdgpu_waves_per_eu(1, 1)))
void lstm_kernel(
    const float* __restrict__ A,      // (T,128,4)
    const float* __restrict__ W_hh,   // (512,128)
    const float* __restrict__ W_fc,   // (5,128)
    const float* __restrict__ b_fc,   // (5,)
    float* __restrict__ out)          // (5,)
{
    const int tid  = threadIdx.x;            // 0..255
    const int lane = tid & 63;
    const int wave = tid >> 6;               // 0..3
    const int q0   = wave * 32;              // first unit of this wave
    const int row  = lane & 15;              // fragment row within tile
    const int kb8  = (lane >> 4) * 8;        // fragment K base (f32 elems)
    const int u1   = q0 + 4 * (lane >> 4) + (lane & 3);  // tile-A unit
    // u2 = u1 + 16 (tile-B unit)

    // h as f16: 2 buffers x 128 f16 = 512 B, linear layout
    __shared__ __align__(16) float h_s[2][64];

    if (tid < 128) ((float*)h_s)[tid] = 0.f;  // h_{-1} = 0 (both bufs)
    __syncthreads();

    // byte offset of this lane's iA fragment; other 7 tiles derived in asm:
    // iB = +0x2000 (16 rows), fA = +0x10000 (128 rows), fB = +0x12000,
    // gA = +0x20000, gB = +0x22000, oA = +0x30000, oB = +0x32000
    const unsigned int wo = (unsigned int)(((q0 + row) * D_LSTM + kb8) * 4);
    const unsigned int atid = (unsigned int)(u1 * 16);  // A byte off (u1 dwordx4; u2 at +256)
    const unsigned int lds0 = (unsigned int)(uintptr_t)&h_s[0][0];
    const unsigned int rb   = lds0 + (unsigned int)((lane >> 4) * 16);  // B-frag read base
    const unsigned int wr   = lds0 + (unsigned int)(u1 * 2);            // h write (u2 at +32)
    const unsigned long long wm  = __ballot((lane & 12) == 0);   // 16 writer lanes
    const unsigned long long sb0 = __ballot(lane & 1);
    const unsigned long long sb1 = __ballot(lane & 2);

    asm volatile(
        // ---- prologue: consts; pack 8 weight tiles f32->f16 into v0-127 ----
        "s_mov_b32 s80, 2048\n\t"
        "s_mov_b32 s86, 4096\n\t"
        "s_mov_b32 s87, 0xBFB8AA3B\n\t"     // -log2(e)
        "s_mov_b32 s88, 0xC038AA3B\n\t"     // -2*log2(e)
        "s_mov_b64 s[82:83], %[wm]\n\t"
        FRAGLOAD("%[wo]")
        ROWPACK(0,1,2,3,4,5,6,7,8,9,10,11,12,13,14,15)                  // iA
        "v_add_u32 v232, 0x10000, %[wo]\n\t"
        FRAGLOAD("v232")
        ROWPACK(16,17,18,19,20,21,22,23,24,25,26,27,28,29,30,31)        // fA
        "v_add_u32 v232, 0x20000, %[wo]\n\t"
        FRAGLOAD("v232")
        ROWPACK(32,33,34,35,36,37,38,39,40,41,42,43,44,45,46,47)        // gA
        "v_add_u32 v232, 0x30000, %[wo]\n\t"
        FRAGLOAD("v232")
        ROWPACK(48,49,50,51,52,53,54,55,56,57,58,59,60,61,62,63)        // oA
        "v_add_u32 v232, 0x2000, %[wo]\n\t"
        FRAGLOAD("v232")
        ROWPACK(64,65,66,67,68,69,70,71,72,73,74,75,76,77,78,79)        // iB
        "v_add_u32 v232, 0x12000, %[wo]\n\t"
        FRAGLOAD("v232")
        ROWPACK(80,81,82,83,84,85,86,87,88,89,90,91,92,93,94,95)        // fB
        "v_add_u32 v232, 0x22000, %[wo]\n\t"
        FRAGLOAD("v232")
        ROWPACK(96,97,98,99,100,101,102,103,104,105,106,107,108,109,110,111)  // gB
        "v_add_u32 v232, 0x32000, %[wo]\n\t"
        FRAGLOAD("v232")
        ROWPACK(112,113,114,115,116,117,118,119,120,121,122,123,124,125,126,127) // oB
        // zeros (mfma C), c states, A row 0
        "v_mov_b32 v200, 0\n\t"
        "v_mov_b32 v201, 0\n\t"
        "v_mov_b32 v202, 0\n\t"
        "v_mov_b32 v203, 0\n\t"
        "v_mov_b32 v228, 0\n\t"
        "v_mov_b32 v229, 0\n\t"
        "global_load_dwordx4 v[176:179], %[at], %[ab]\n\t"
        "global_load_dwordx4 v[180:183], %[at], %[ab] offset:256\n\t"
        "s_waitcnt vmcnt(0)\n\t"
        "1:\n\t"
        // even step: read buf0, consume v176-183, prefetch v184-191, write buf1
        HALF(184,187,188,191, 176,177,178,179,180,181,182,183, 0,64,128,192, 256,288)
        // odd step: read buf1, consume v184-191, prefetch v176-183, write buf0
        HALF(176,179,180,183, 184,185,186,187,188,189,190,191, 256,320,384,448, 0,32)
        "s_sub_u32 s86, s86, 1\n\t"
        "s_cmp_lg_u32 s86, 0\n\t"
        "s_cbranch_scc1 1b\n\t"
        :
        : [whh]"s"(W_hh), [wo]"v"(wo), [ab]"s"(A), [at]"v"(atid),
          [rb]"v"(rb), [wr]"v"(wr), [wm]"s"(wm), [sb0]"s"(sb0), [sb1]"s"(sb1)
        : "v0","v1","v2","v3","v4","v5","v6","v7","v8","v9",
          "v10","v11","v12","v13","v14","v15","v16","v17","v18","v19",
          "v20","v21","v22","v23","v24","v25","v26","v27","v28","v29",
          "v30","v31","v32","v33","v34","v35","v36","v37","v38","v39",
          "v40","v41","v42","v43","v44","v45","v46","v47","v48","v49",
          "v50","v51","v52","v53","v54","v55","v56","v57","v58","v59",
          "v60","v61","v62","v63","v64","v65","v66","v67","v68","v69",
          "v70","v71","v72","v73","v74","v75","v76","v77","v78","v79",
          "v80","v81","v82","v83","v84","v85","v86","v87","v88","v89",
          "v90","v91","v92","v93","v94","v95","v96","v97","v98","v99",
          "v100","v101","v102","v103","v104","v105","v106","v107","v108","v109",
          "v110","v111","v112","v113","v114","v115","v116","v117","v118","v119",
          "v120","v121","v122","v123","v124","v125","v126","v127","v128","v129",
          "v130","v131","v132","v133","v134","v135","v136","v137","v138","v139",
          "v140","v141","v142","v143","v144","v145","v146","v147","v148","v149",
          "v150","v151","v152","v153","v154","v155","v156","v157","v158","v159",
          "v160","v161","v162","v163","v164","v165","v166","v167","v168","v169",
          "v170","v171","v172","v173","v174","v175","v176","v177","v178","v179",
          "v180","v181","v182","v183","v184","v185","v186","v187","v188","v189",
          "v190","v191","v192","v193","v194","v195","v196","v197","v198","v199",
          "v200","v201","v202","v203","v204","v205","v206","v207","v208","v209",
          "v210","v211","v212","v213","v214","v215","v216","v217","v218","v219",
          "v220","v221","v222","v223","v224","v225","v226","v227","v228","v229",
          "v230","v231","v232","v233","v234","v235",
          "s80","s81","s82","s83","s84","s85","s86","s87","s88",
          "scc","memory"
    );

    __syncthreads();

    // final FC: out = hT @ W_fc.T + b_fc  (final h in buffer 0, f16, linear)
    if (tid < N_CLS) {
        const __half* hh = (const __half*)&h_s[0][0];
        float acc = b_fc[tid];
        #pragma unroll
        for (int k = 0; k < D_LSTM; ++k) {
            acc += __half2float(hh[k]) * W_fc[tid * D_LSTM + k];
        }
        out[tid] = acc;
    }
}

// ---------------------------------------------------------------------------
extern "C" void kernel_launch(void* const* d_in, const int* in_sizes, int n_in,
                              void* d_out, int out_size, void* d_ws, size_t ws_size,
                              hipStream_t stream) {
    const float* x       = (const float*)d_in[0];
    const int*   esrc    = (const int*)  d_in[1];
    const int*   edst    = (const int*)  d_in[2];
    const float* W_rel1  = (const float*)d_in[3];
    const float* b_rel1  = (const float*)d_in[4];
    const float* W_root1 = (const float*)d_in[5];
    const float* W_rel2  = (const float*)d_in[6];
    const float* b_rel2  = (const float*)d_in[7];
    const float* W_root2 = (const float*)d_in[8];
    const float* W_ih    = (const float*)d_in[9];
    const float* W_hh    = (const float*)d_in[10];
    const float* b_ih    = (const float*)d_in[11];
    const float* b_hh    = (const float*)d_in[12];
    const float* W_fc    = (const float*)d_in[13];
    const float* b_fc    = (const float*)d_in[14];

    float* out = (float*)d_out;
    float* A   = (float*)d_ws;   // (T,128,4) f32 = 16 MB

    gnn_proj_kernel<<<T_LEN / TB, 64, 0, stream>>>(
        x, esrc, edst, W_rel1, b_rel1, W_root1,
        W_rel2, b_rel2, W_root2, W_ih, b_ih, b_hh, A);

    lstm_kernel<<<1, 256, 0, stream>>>(A, W_hh, W_fc, b_fc, out);
}

// Round 21
// 3730.865 us; speedup vs baseline: 1.3163x; 1.3163x over previous
//
#include <hip/hip_runtime.h>
#include <hip/hip_fp16.h>

#define T_LEN 8192
#define N_NODES 33
#define N_EDGES 64
#define DIM_IN 3
#define D_H 64
#define D_LSTM 128
#define N_CLS 5
#define TB 4   // timesteps per block in kernel 1

typedef float v2f __attribute__((ext_vector_type(2)));
typedef float v4f __attribute__((ext_vector_type(4)));

// ---------------------------------------------------------------------------
// Kernel 1: graph conv x2 + relu + mean over nodes + input-side LSTM projection
// Writes A in (T, 128, 4) layout: A[(t*128+q)*4 + g] = gate g of unit q
// (g: 0=i, 1=f, 2=g, 3=o).  LSTM lane scalar-loads gate rr of its unit.
// ---------------------------------------------------------------------------
__global__ __launch_bounds__(64, 2) void gnn_proj_kernel(
    const float* __restrict__ x,        // (T,33,3)
    const int*   __restrict__ esrc,     // (64,)
    const int*   __restrict__ edst,     // (64,)
    const float* __restrict__ W_rel1,   // (64,3)
    const float* __restrict__ b_rel1,   // (64,)
    const float* __restrict__ W_root1,  // (64,3)
    const float* __restrict__ W_rel2,   // (64,64)
    const float* __restrict__ b_rel2,   // (64,)
    const float* __restrict__ W_root2,  // (64,64)
    const float* __restrict__ W_ih,     // (512,64)
    const float* __restrict__ b_ih,     // (512,)
    const float* __restrict__ b_hh,     // (512,)
    float* __restrict__ A)              // (T,128,4)  [workspace]
{
    const int t0 = blockIdx.x * TB;
    const int j  = threadIdx.x;   // 0..63

    __shared__ __align__(16) float x_s[N_NODES][DIM_IN];
    __shared__ __align__(16) float agg1[N_NODES][DIM_IN];
    __shared__ __align__(16) float h1[N_NODES][D_H];
    __shared__ __align__(16) float agg2[N_NODES][D_H];
    __shared__ __align__(16) float seq_s[TB][D_H];
    __shared__ int es[N_EDGES], ed[N_EDGES];

    es[j] = esrc[j];
    ed[j] = edst[j];

    const float wr1_0 = W_rel1[j*3+0], wr1_1 = W_rel1[j*3+1], wr1_2 = W_rel1[j*3+2];
    const float wt1_0 = W_root1[j*3+0], wt1_1 = W_root1[j*3+1], wt1_2 = W_root1[j*3+2];
    const float br1 = b_rel1[j];
    const float br2 = b_rel2[j];

    float wr2[D_H], wt2[D_H];
    #pragma unroll
    for (int k = 0; k < D_H; ++k) {
        wr2[k] = W_rel2[j*D_H + k];
        wt2[k] = W_root2[j*D_H + k];
    }

    for (int tt = 0; tt < TB; ++tt) {
        const int t = t0 + tt;
        __syncthreads();

        const float* xt = x + (size_t)t * (N_NODES * DIM_IN);
        for (int i = j; i < N_NODES * DIM_IN; i += 64) x_s[0][i] = xt[i];
        __syncthreads();

        if (j < N_NODES) {
            float a0 = 0.f, a1 = 0.f, a2 = 0.f;
            for (int e = 0; e < N_EDGES; ++e) {
                if (ed[e] == j) {
                    a0 += x_s[es[e]][0];
                    a1 += x_s[es[e]][1];
                    a2 += x_s[es[e]][2];
                }
            }
            agg1[j][0] = a0; agg1[j][1] = a1; agg1[j][2] = a2;
        }
        __syncthreads();

        for (int n = 0; n < N_NODES; ++n) {
            float v = br1
                + agg1[n][0]*wr1_0 + agg1[n][1]*wr1_1 + agg1[n][2]*wr1_2
                + x_s[n][0]*wt1_0  + x_s[n][1]*wt1_1  + x_s[n][2]*wt1_2;
            h1[n][j]  = v;
            agg2[n][j] = 0.f;
        }
        __syncthreads();

        for (int e = 0; e < N_EDGES; ++e) {
            agg2[ed[e]][j] += h1[es[e]][j];
        }
        __syncthreads();

        float seqv = 0.f;
        for (int n = 0; n < N_NODES; ++n) {
            const float4* ag4 = (const float4*)agg2[n];
            const float4* h4  = (const float4*)h1[n];
            float acc0 = br2, acc1 = 0.f, acc2 = 0.f, acc3 = 0.f;
            #pragma unroll
            for (int k4 = 0; k4 < D_H/4; ++k4) {
                float4 av = ag4[k4];
                float4 hv = h4[k4];
                acc0 += av.x * wr2[4*k4+0] + hv.x * wt2[4*k4+0];
                acc1 += av.y * wr2[4*k4+1] + hv.y * wt2[4*k4+1];
                acc2 += av.z * wr2[4*k4+2] + hv.z * wt2[4*k4+2];
                acc3 += av.w * wr2[4*k4+3] + hv.w * wt2[4*k4+3];
            }
            float acc = (acc0 + acc1) + (acc2 + acc3);
            seqv += fmaxf(acc, 0.f);
        }
        seq_s[tt][j] = seqv * (1.0f / 33.0f);
    }
    __syncthreads();

    #pragma unroll
    for (int m = 0; m < 8; ++m) {
        const int o = m * 64 + j;
        const float bias = b_ih[o] + b_hh[o];
        const float4* w4 = (const float4*)(W_ih + (size_t)o * D_H);
        float acc[TB];
        #pragma unroll
        for (int tt = 0; tt < TB; ++tt) acc[tt] = bias;
        #pragma unroll
        for (int k4 = 0; k4 < D_H/4; ++k4) {
            float4 wv = w4[k4];
            #pragma unroll
            for (int tt = 0; tt < TB; ++tt) {
                const float4* s4 = (const float4*)seq_s[tt];
                float4 sv = s4[k4];
                acc[tt] += sv.x*wv.x + sv.y*wv.y + sv.z*wv.z + sv.w*wv.w;
            }
        }
        // (T,128,4) layout: q = o&127, g = o>>7
        #pragma unroll
        for (int tt = 0; tt < TB; ++tt) {
            A[((size_t)(t0 + tt) * 128 + (o & 127)) * 4 + (o >> 7)] = acc[tt];
        }
    }
}

// ---------------------------------------------------------------------------
// Kernel 2 (round 21 = round 20 with row_ror direction fix):
// r20 failed with the PRE-REGISTERED tell (bounded absmax ~0.29) for an
// inverted row_ror convention: on gfx950 row_ror:N delivers from lane
// (l-N) mod 16, so ror:4 carries rr=3 (sigma_o) and ror:12 carries rr=1
// (sigma_f) into writer lanes; ror:8 (tanh g) is direction-invariant.
// Fix: swap v184<->v186 at the two consumers (c uses v186 as sf, h uses
// v184 as so).  Everything else byte-identical to r20:
// 8 waves 2/SIMD MFMA structure (r18-proven) + per-lane nonlin split
// (rr=(l>>2)&3 computes ONE gate: 1 exp + 1 rcp), per-lane scalar A bias.
// ---------------------------------------------------------------------------

#define CVTPK(D,S0,S1) \
  "v_cvt_f16_f32 v190, v" #S0 "\n\t" \
  "v_cvt_f16_f32 v191, v" #S1 "\n\t" \
  "v_and_b32 v190, 0xffff, v190\n\t" \
  "v_lshlrev_b32 v191, 16, v191\n\t" \
  "v_or_b32 v" #D ", v190, v191\n\t"

#define ROWPACK(D0,D1,D2,D3,D4,D5,D6,D7,D8,D9,D10,D11,D12,D13,D14,D15) \
  CVTPK(D0,128,129) CVTPK(D1,130,131) CVTPK(D2,132,133) CVTPK(D3,134,135) \
  CVTPK(D4,136,137) CVTPK(D5,138,139) CVTPK(D6,140,141) CVTPK(D7,142,143) \
  CVTPK(D8,144,145) CVTPK(D9,146,147) CVTPK(D10,148,149) CVTPK(D11,150,151) \
  CVTPK(D12,152,153) CVTPK(D13,154,155) CVTPK(D14,156,157) CVTPK(D15,158,159)

// fragment loads: 8 f32 per K-chunk kt at byte offsets kt*128 (32 f32 cols)
#define FRAGLOAD(WA) \
  "global_load_dwordx4 v[128:131], %[" #WA "], off\n\t" \
  "global_load_dwordx4 v[132:135], %[" #WA "], off offset:16\n\t" \
  "global_load_dwordx4 v[136:139], %[" #WA "], off offset:128\n\t" \
  "global_load_dwordx4 v[140:143], %[" #WA "], off offset:144\n\t" \
  "global_load_dwordx4 v[144:147], %[" #WA "], off offset:256\n\t" \
  "global_load_dwordx4 v[148:151], %[" #WA "], off offset:272\n\t" \
  "global_load_dwordx4 v[152:155], %[" #WA "], off offset:384\n\t" \
  "global_load_dwordx4 v[156:159], %[" #WA "], off offset:400\n\t" \
  "s_waitcnt vmcnt(0)\n\t"

// P = prefetch dest reg (next step's A scalar), PC = consume reg
#define HALF(P, PC, R0,R1,R2,R3, WOFF) \
  "ds_read_b128 v[64:67], %[rb] offset:" #R0 "\n\t" \
  "ds_read_b128 v[68:71], %[rb] offset:" #R1 "\n\t" \
  "ds_read_b128 v[72:75], %[rb] offset:" #R2 "\n\t" \
  "ds_read_b128 v[76:79], %[rb] offset:" #R3 "\n\t" \
  "v_add_u32 v189, s80, %[at]\n\t" \
  "global_load_dword v" #P ", v189, %[ab]\n\t" \
  "s_add_u32 s80, s80, 2048\n\t" \
  "s_cmp_lg_u32 s80, 0x1000000\n\t" \
  "s_cselect_b32 s80, s80, 0\n\t" \
  "s_waitcnt lgkmcnt(0)\n\t" \
  /* 16 mfma: 4 gate chains x 4 K-chunks (r18-proven) */ \
  "v_mfma_f32_16x16x32_f16 v[80:83], v[0:3],   v[64:67], v[164:167]\n\t" \
  "v_mfma_f32_16x16x32_f16 v[84:87], v[16:19], v[64:67], v[164:167]\n\t" \
  "v_mfma_f32_16x16x32_f16 v[88:91], v[32:35], v[64:67], v[164:167]\n\t" \
  "v_mfma_f32_16x16x32_f16 v[92:95], v[48:51], v[64:67], v[164:167]\n\t" \
  "v_mfma_f32_16x16x32_f16 v[80:83], v[4:7],   v[68:71], v[80:83]\n\t" \
  "v_mfma_f32_16x16x32_f16 v[84:87], v[20:23], v[68:71], v[84:87]\n\t" \
  "v_mfma_f32_16x16x32_f16 v[88:91], v[36:39], v[68:71], v[88:91]\n\t" \
  "v_mfma_f32_16x16x32_f16 v[92:95], v[52:55], v[68:71], v[92:95]\n\t" \
  "v_mfma_f32_16x16x32_f16 v[80:83], v[8:11],  v[72:75], v[80:83]\n\t" \
  "v_mfma_f32_16x16x32_f16 v[84:87], v[24:27], v[72:75], v[84:87]\n\t" \
  "v_mfma_f32_16x16x32_f16 v[88:91], v[40:43], v[72:75], v[88:91]\n\t" \
  "v_mfma_f32_16x16x32_f16 v[92:95], v[56:59], v[72:75], v[92:95]\n\t" \
  "v_mfma_f32_16x16x32_f16 v[80:83], v[12:15], v[76:79], v[80:83]\n\t" \
  "v_mfma_f32_16x16x32_f16 v[84:87], v[28:31], v[76:79], v[84:87]\n\t" \
  "v_mfma_f32_16x16x32_f16 v[88:91], v[44:47], v[76:79], v[88:91]\n\t" \
  "v_mfma_f32_16x16x32_f16 v[92:95], v[60:63], v[76:79], v[92:95]\n\t" \
  "s_nop 7\n\t" \
  "s_nop 7\n\t" \
  /* D-select r = lane&3 per gate -> v176=i v177=f v178=g v179=o of unit u */ \
  "v_cndmask_b32 v184, v80, v82, %[sb1]\n\t" \
  "v_cndmask_b32 v185, v81, v83, %[sb1]\n\t" \
  "v_cndmask_b32 v176, v184, v185, %[sb0]\n\t" \
  "v_cndmask_b32 v184, v84, v86, %[sb1]\n\t" \
  "v_cndmask_b32 v185, v85, v87, %[sb1]\n\t" \
  "v_cndmask_b32 v177, v184, v185, %[sb0]\n\t" \
  "v_cndmask_b32 v184, v88, v90, %[sb1]\n\t" \
  "v_cndmask_b32 v185, v89, v91, %[sb1]\n\t" \
  "v_cndmask_b32 v178, v184, v185, %[sb0]\n\t" \
  "v_cndmask_b32 v184, v92, v94, %[sb1]\n\t" \
  "v_cndmask_b32 v185, v93, v95, %[sb1]\n\t" \
  "v_cndmask_b32 v179, v184, v185, %[sb0]\n\t" \
  /* gate-select rr=(l>>2)&3: x = gate rr of u */ \
  "v_cndmask_b32 v180, v176, v177, %[sb2]\n\t" \
  "v_cndmask_b32 v181, v178, v179, %[sb2]\n\t" \
  "v_cndmask_b32 v182, v180, v181, %[sb3]\n\t" \
  /* + per-lane A bias (scalar, prefetched) */ \
  "s_waitcnt vmcnt(1)\n\t" \
  "v_add_f32 v182, v182, v" #PC "\n\t" \
  /* per-lane nonlin: y = rcp(1+exp2(m1*x))*sc + ad */ \
  "v_mul_f32 v183, %[m1], v182\n\t" \
  "v_exp_f32 v183, v183\n\t" \
  "s_nop 1\n\t" \
  "v_add_f32 v183, 1.0, v183\n\t" \
  "v_rcp_f32 v183, v183\n\t" \
  "s_nop 1\n\t" \
  "v_fma_f32 v183, v183, %[sc], %[ad]\n\t" \
  "s_nop 1\n\t" \
  /* gather quad gates. gfx950 row_ror:N delivers FROM lane (l-N)&15: */ \
  /* v184 (ror:4)  <- l+12 -> sigma_o ; v185 (ror:8) <- l+8 -> tanh g ; */ \
  /* v186 (ror:12) <- l+4  -> sigma_f   (in writer lanes rr=0)         */ \
  "v_mov_b32_dpp v184, v183 row_ror:4 row_mask:0xf bank_mask:0xf\n\t" \
  "v_mov_b32_dpp v185, v183 row_ror:8 row_mask:0xf bank_mask:0xf\n\t" \
  "v_mov_b32_dpp v186, v183 row_ror:12 row_mask:0xf bank_mask:0xf\n\t" \
  /* c = sf*c + si*tg  (valid in writer lanes; sf = v186) */ \
  "v_mul_f32 v187, v183, v185\n\t" \
  "v_fma_f32 v190, v186, v190, v187\n\t" \
  /* tanh(c) */ \
  "v_mul_f32 v188, s88, v190\n\t" \
  "v_exp_f32 v188, v188\n\t" \
  "s_nop 1\n\t" \
  "v_add_f32 v188, 1.0, v188\n\t" \
  "v_rcp_f32 v188, v188\n\t" \
  "s_nop 1\n\t" \
  "v_fma_f32 v188, v188, 2.0, -1.0\n\t" \
  "v_mul_f32 v188, v184, v188\n\t" \
  "v_cvt_f16_f32 v188, v188\n\t" \
  /* write h f16 (lanes with (l&12)==0) */ \
  "s_and_saveexec_b64 s[84:85], s[82:83]\n\t" \
  "ds_write_b16 %[wr], v188 offset:" #WOFF "\n\t" \
  "s_mov_b64 exec, s[84:85]\n\t" \
  "s_waitcnt lgkmcnt(0)\n\t" \
  "s_barrier\n\t"

__global__ __launch_bounds__(512, 2)
__attribute__((amdgpu_waves_per_eu(2, 2)))
void lstm_kernel(
    const float* __restrict__ A,      // (T,128,4)
    const float* __restrict__ W_hh,   // (512,128)
    const float* __restrict__ W_fc,   // (5,128)
    const float* __restrict__ b_fc,   // (5,)
    float* __restrict__ out)          // (5,)
{
    const int tid  = threadIdx.x;            // 0..511
    const int lane = tid & 63;
    const int wave = tid >> 6;               // 0..7
    const int q0   = wave * 16;              // first unit of this wave
    const int row  = lane & 15;              // A-fragment row
    const int kb8  = (lane >> 4) * 8;        // A/B fragment K-chunk base
    const int u    = q0 + 4 * (lane >> 4) + (lane & 3);  // this lane's unit
    const int rr   = (lane >> 2) & 3;        // redundancy group = own gate

    // h as f16: 2 buffers x 128 f16 = 512 B, linear layout
    __shared__ __align__(16) float h_s[2][64];

    if (tid < 128) ((float*)h_s)[tid] = 0.f;  // h_{-1} = 0 (both bufs)
    __syncthreads();

    // per-lane fragment addresses (row l&15, K base (l>>4)*8; kt via imm offs)
    const unsigned long long wai = (unsigned long long)(uintptr_t)(W_hh + (size_t)(q0 + row)        * D_LSTM + kb8);
    const unsigned long long waf = (unsigned long long)(uintptr_t)(W_hh + (size_t)(128 + q0 + row)  * D_LSTM + kb8);
    const unsigned long long wag = (unsigned long long)(uintptr_t)(W_hh + (size_t)(256 + q0 + row)  * D_LSTM + kb8);
    const unsigned long long wao = (unsigned long long)(uintptr_t)(W_hh + (size_t)(384 + q0 + row)  * D_LSTM + kb8);
    const unsigned int atid = (unsigned int)(u * 16 + rr * 4);   // A byte off (own gate scalar)
    const unsigned int lds0 = (unsigned int)(uintptr_t)&h_s[0][0];
    const unsigned int rb   = lds0 + (unsigned int)((lane >> 4) * 16);  // B-frag read base
    const unsigned int wr   = lds0 + (unsigned int)(u * 2);             // h write addr
    const unsigned long long wm  = __ballot((lane & 12) == 0);   // 16 writer lanes
    const unsigned long long sb0 = __ballot(lane & 1);
    const unsigned long long sb1 = __ballot(lane & 2);
    const unsigned long long sb2 = __ballot(lane & 4);
    const unsigned long long sb3 = __ballot(lane & 8);
    const float m1 = (rr == 2) ? -2.8853900817779268f  // -2*log2(e) -> tanh
                               : -1.4426950408889634f; // -log2(e)   -> sigmoid
    const float sc = (rr == 2) ? 2.0f : 1.0f;
    const float ad = (rr == 2) ? -1.0f : 0.0f;

    asm volatile(
        // ---- prologue: consts; pack weight fragments f32->f16 into v0-63 ----
        "s_mov_b32 s80, 2048\n\t"
        "s_mov_b32 s86, 4096\n\t"
        "s_mov_b32 s88, 0xC038AA3B\n\t"     // -2*log2(e)
        "s_mov_b64 s[82:83], %[wm]\n\t"
        FRAGLOAD(wai)
        ROWPACK(0,1,2,3,4,5,6,7,8,9,10,11,12,13,14,15)
        FRAGLOAD(waf)
        ROWPACK(16,17,18,19,20,21,22,23,24,25,26,27,28,29,30,31)
        FRAGLOAD(wag)
        ROWPACK(32,33,34,35,36,37,38,39,40,41,42,43,44,45,46,47)
        FRAGLOAD(wao)
        ROWPACK(48,49,50,51,52,53,54,55,56,57,58,59,60,61,62,63)
        // zero C operand + c state; load A row 0 (own-gate scalar)
        "v_mov_b32 v164, 0\n\t"
        "v_mov_b32 v165, 0\n\t"
        "v_mov_b32 v166, 0\n\t"
        "v_mov_b32 v167, 0\n\t"
        "global_load_dword v168, %[at], %[ab]\n\t"
        "s_waitcnt vmcnt(0)\n\t"
        "v_mov_b32 v190, 0\n\t"             // c = 0
        "1:\n\t"
        // even step: read buf0 (+0), consume v168, prefetch v172, write buf1 (+256)
        HALF(172, 168, 0,64,128,192, 256)
        // odd step: read buf1 (+256), consume v172, prefetch v168, write buf0 (+0)
        HALF(168, 172, 256,320,384,448, 0)
        "s_sub_u32 s86, s86, 1\n\t"
        "s_cmp_lg_u32 s86, 0\n\t"
        "s_cbranch_scc1 1b\n\t"
        :
        : [wai]"v"(wai), [waf]"v"(waf), [wag]"v"(wag), [wao]"v"(wao),
          [ab]"s"(A), [at]"v"(atid), [rb]"v"(rb), [wr]"v"(wr), [wm]"s"(wm),
          [sb0]"s"(sb0), [sb1]"s"(sb1), [sb2]"s"(sb2), [sb3]"s"(sb3),
          [m1]"v"(m1), [sc]"v"(sc), [ad]"v"(ad)
        : "v0","v1","v2","v3","v4","v5","v6","v7","v8","v9",
          "v10","v11","v12","v13","v14","v15","v16","v17","v18","v19",
          "v20","v21","v22","v23","v24","v25","v26","v27","v28","v29",
          "v30","v31","v32","v33","v34","v35","v36","v37","v38","v39",
          "v40","v41","v42","v43","v44","v45","v46","v47","v48","v49",
          "v50","v51","v52","v53","v54","v55","v56","v57","v58","v59",
          "v60","v61","v62","v63","v64","v65","v66","v67","v68","v69",
          "v70","v71","v72","v73","v74","v75","v76","v77","v78","v79",
          "v80","v81","v82","v83","v84","v85","v86","v87","v88","v89",
          "v90","v91","v92","v93","v94","v95","v96","v97","v98","v99",
          "v100","v101","v102","v103","v104","v105","v106","v107","v108","v109",
          "v110","v111","v112","v113","v114","v115","v116","v117","v118","v119",
          "v120","v121","v122","v123","v124","v125","v126","v127","v128","v129",
          "v130","v131","v132","v133","v134","v135","v136","v137","v138","v139",
          "v140","v141","v142","v143","v144","v145","v146","v147","v148","v149",
          "v150","v151","v152","v153","v154","v155","v156","v157","v158","v159",
          "v160","v161","v162","v163","v164","v165","v166","v167","v168","v169",
          "v170","v171","v172","v173","v174","v175","v176","v177","v178","v179",
          "v180","v181","v182","v183","v184","v185","v186","v187","v188","v189",
          "v190","v191",
          "s80","s81","s82","s83","s84","s85","s86","s87","s88",
          "scc","memory"
    );

    __syncthreads();

    // final FC: out = hT @ W_fc.T + b_fc  (final h in buffer 0, f16, linear)
    if (tid < N_CLS) {
        const __half* hh = (const __half*)&h_s[0][0];
        float acc = b_fc[tid];
        #pragma unroll
        for (int k = 0; k < D_LSTM; ++k) {
            acc += __half2float(hh[k]) * W_fc[tid * D_LSTM + k];
        }
        out[tid] = acc;
    }
}

// ---------------------------------------------------------------------------
extern "C" void kernel_launch(void* const* d_in, const int* in_sizes, int n_in,
                              void* d_out, int out_size, void* d_ws, size_t ws_size,
                              hipStream_t stream) {
    const float* x       = (const float*)d_in[0];
    const int*   esrc    = (const int*)  d_in[1];
    const int*   edst    = (const int*)  d_in[2];
    const float* W_rel1  = (const float*)d_in[3];
    const float* b_rel1  = (const float*)d_in[4];
    const float* W_root1 = (const float*)d_in[5];
    const float* W_rel2  = (const float*)d_in[6];
    const float* b_rel2  = (const float*)d_in[7];
    const float* W_root2 = (const float*)d_in[8];
    const float* W_ih    = (const float*)d_in[9];
    const float* W_hh    = (const float*)d_in[10];
    const float* b_ih    = (const float*)d_in[11];
    const float* b_hh    = (const float*)d_in[12];
    const float* W_fc    = (const float*)d_in[13];
    const float* b_fc    = (const float*)d_in[14];

    float* out = (float*)d_out;
    float* A   = (float*)d_ws;   // (T,128,4) f32 = 16 MB

    gnn_proj_kernel<<<T_LEN / TB, 64, 0, stream>>>(
        x, esrc, edst, W_rel1, b_rel1, W_root1,
        W_rel2, b_rel2, W_root2, W_ih, b_ih, b_hh, A);

    lstm_kernel<<<1, 512, 0, stream>>>(A, W_hh, W_fc, b_fc, out);
}

// Round 22
// 3580.624 us; speedup vs baseline: 1.3715x; 1.0420x over previous
//
#include <hip/hip_runtime.h>
#include <hip/hip_fp16.h>

#define T_LEN 8192
#define N_NODES 33
#define N_EDGES 64
#define DIM_IN 3
#define D_H 64
#define D_LSTM 128
#define N_CLS 5
#define TB 4   // timesteps per block in kernel 1

typedef float v2f __attribute__((ext_vector_type(2)));
typedef float v4f __attribute__((ext_vector_type(4)));

// ---------------------------------------------------------------------------
// Kernel 1: graph conv x2 + relu + mean over nodes + input-side LSTM projection
// Writes A in (T, 128, 4) layout: A[(t*128+q)*4 + g] = gate g of unit q
// (g: 0=i, 1=f, 2=g, 3=o).  LSTM lane scalar-loads gate rr of its unit.
// ---------------------------------------------------------------------------
__global__ __launch_bounds__(64, 2) void gnn_proj_kernel(
    const float* __restrict__ x,        // (T,33,3)
    const int*   __restrict__ esrc,     // (64,)
    const int*   __restrict__ edst,     // (64,)
    const float* __restrict__ W_rel1,   // (64,3)
    const float* __restrict__ b_rel1,   // (64,)
    const float* __restrict__ W_root1,  // (64,3)
    const float* __restrict__ W_rel2,   // (64,64)
    const float* __restrict__ b_rel2,   // (64,)
    const float* __restrict__ W_root2,  // (64,64)
    const float* __restrict__ W_ih,     // (512,64)
    const float* __restrict__ b_ih,     // (512,)
    const float* __restrict__ b_hh,     // (512,)
    float* __restrict__ A)              // (T,128,4)  [workspace]
{
    const int t0 = blockIdx.x * TB;
    const int j  = threadIdx.x;   // 0..63

    __shared__ __align__(16) float x_s[N_NODES][DIM_IN];
    __shared__ __align__(16) float agg1[N_NODES][DIM_IN];
    __shared__ __align__(16) float h1[N_NODES][D_H];
    __shared__ __align__(16) float agg2[N_NODES][D_H];
    __shared__ __align__(16) float seq_s[TB][D_H];
    __shared__ int es[N_EDGES], ed[N_EDGES];

    es[j] = esrc[j];
    ed[j] = edst[j];

    const float wr1_0 = W_rel1[j*3+0], wr1_1 = W_rel1[j*3+1], wr1_2 = W_rel1[j*3+2];
    const float wt1_0 = W_root1[j*3+0], wt1_1 = W_root1[j*3+1], wt1_2 = W_root1[j*3+2];
    const float br1 = b_rel1[j];
    const float br2 = b_rel2[j];

    float wr2[D_H], wt2[D_H];
    #pragma unroll
    for (int k = 0; k < D_H; ++k) {
        wr2[k] = W_rel2[j*D_H + k];
        wt2[k] = W_root2[j*D_H + k];
    }

    for (int tt = 0; tt < TB; ++tt) {
        const int t = t0 + tt;
        __syncthreads();

        const float* xt = x + (size_t)t * (N_NODES * DIM_IN);
        for (int i = j; i < N_NODES * DIM_IN; i += 64) x_s[0][i] = xt[i];
        __syncthreads();

        if (j < N_NODES) {
            float a0 = 0.f, a1 = 0.f, a2 = 0.f;
            for (int e = 0; e < N_EDGES; ++e) {
                if (ed[e] == j) {
                    a0 += x_s[es[e]][0];
                    a1 += x_s[es[e]][1];
                    a2 += x_s[es[e]][2];
                }
            }
            agg1[j][0] = a0; agg1[j][1] = a1; agg1[j][2] = a2;
        }
        __syncthreads();

        for (int n = 0; n < N_NODES; ++n) {
            float v = br1
                + agg1[n][0]*wr1_0 + agg1[n][1]*wr1_1 + agg1[n][2]*wr1_2
                + x_s[n][0]*wt1_0  + x_s[n][1]*wt1_1  + x_s[n][2]*wt1_2;
            h1[n][j]  = v;
            agg2[n][j] = 0.f;
        }
        __syncthreads();

        for (int e = 0; e < N_EDGES; ++e) {
            agg2[ed[e]][j] += h1[es[e]][j];
        }
        __syncthreads();

        float seqv = 0.f;
        for (int n = 0; n < N_NODES; ++n) {
            const float4* ag4 = (const float4*)agg2[n];
            const float4* h4  = (const float4*)h1[n];
            float acc0 = br2, acc1 = 0.f, acc2 = 0.f, acc3 = 0.f;
            #pragma unroll
            for (int k4 = 0; k4 < D_H/4; ++k4) {
                float4 av = ag4[k4];
                float4 hv = h4[k4];
                acc0 += av.x * wr2[4*k4+0] + hv.x * wt2[4*k4+0];
                acc1 += av.y * wr2[4*k4+1] + hv.y * wt2[4*k4+1];
                acc2 += av.z * wr2[4*k4+2] + hv.z * wt2[4*k4+2];
                acc3 += av.w * wr2[4*k4+3] + hv.w * wt2[4*k4+3];
            }
            float acc = (acc0 + acc1) + (acc2 + acc3);
            seqv += fmaxf(acc, 0.f);
        }
        seq_s[tt][j] = seqv * (1.0f / 33.0f);
    }
    __syncthreads();

    #pragma unroll
    for (int m = 0; m < 8; ++m) {
        const int o = m * 64 + j;
        const float bias = b_ih[o] + b_hh[o];
        const float4* w4 = (const float4*)(W_ih + (size_t)o * D_H);
        float acc[TB];
        #pragma unroll
        for (int tt = 0; tt < TB; ++tt) acc[tt] = bias;
        #pragma unroll
        for (int k4 = 0; k4 < D_H/4; ++k4) {
            float4 wv = w4[k4];
            #pragma unroll
            for (int tt = 0; tt < TB; ++tt) {
                const float4* s4 = (const float4*)seq_s[tt];
                float4 sv = s4[k4];
                acc[tt] += sv.x*wv.x + sv.y*wv.y + sv.z*wv.z + sv.w*wv.w;
            }
        }
        // (T,128,4) layout: q = o&127, g = o>>7
        #pragma unroll
        for (int tt = 0; tt < TB; ++tt) {
            A[((size_t)(t0 + tt) * 128 + (o & 127)) * 4 + (o >> 7)] = acc[tt];
        }
    }
}

// ---------------------------------------------------------------------------
// Kernel 2 (round 22 = round 21 + latency-schedule polish):
//  (a) staggered lgkmcnt(3/2/1/0): mfma chunk k waits only for h-read k,
//      so chunk-0 mfma issue while reads 1-3 are still in flight (DS
//      completes in order; r21 waited for ALL reads = ~120cyc exposed).
//  (b) single s_nop 7 after the mfma block (was 2): the first select reads
//      v[80:83] whose last write is mfma #13/16 (~12cyc stale) and v[92:95]
//      (o, written by mfma #16) is first read ~36cyc later in the select
//      tree - one nop covers the worst case.
// Everything else byte-identical to r21 (8 waves 2/SIMD, MFMA matvec,
// per-lane nonlin split, row_ror gather with gfx950 (l-N) convention).
// ---------------------------------------------------------------------------

#define CVTPK(D,S0,S1) \
  "v_cvt_f16_f32 v190, v" #S0 "\n\t" \
  "v_cvt_f16_f32 v191, v" #S1 "\n\t" \
  "v_and_b32 v190, 0xffff, v190\n\t" \
  "v_lshlrev_b32 v191, 16, v191\n\t" \
  "v_or_b32 v" #D ", v190, v191\n\t"

#define ROWPACK(D0,D1,D2,D3,D4,D5,D6,D7,D8,D9,D10,D11,D12,D13,D14,D15) \
  CVTPK(D0,128,129) CVTPK(D1,130,131) CVTPK(D2,132,133) CVTPK(D3,134,135) \
  CVTPK(D4,136,137) CVTPK(D5,138,139) CVTPK(D6,140,141) CVTPK(D7,142,143) \
  CVTPK(D8,144,145) CVTPK(D9,146,147) CVTPK(D10,148,149) CVTPK(D11,150,151) \
  CVTPK(D12,152,153) CVTPK(D13,154,155) CVTPK(D14,156,157) CVTPK(D15,158,159)

// fragment loads: 8 f32 per K-chunk kt at byte offsets kt*128 (32 f32 cols)
#define FRAGLOAD(WA) \
  "global_load_dwordx4 v[128:131], %[" #WA "], off\n\t" \
  "global_load_dwordx4 v[132:135], %[" #WA "], off offset:16\n\t" \
  "global_load_dwordx4 v[136:139], %[" #WA "], off offset:128\n\t" \
  "global_load_dwordx4 v[140:143], %[" #WA "], off offset:144\n\t" \
  "global_load_dwordx4 v[144:147], %[" #WA "], off offset:256\n\t" \
  "global_load_dwordx4 v[148:151], %[" #WA "], off offset:272\n\t" \
  "global_load_dwordx4 v[152:155], %[" #WA "], off offset:384\n\t" \
  "global_load_dwordx4 v[156:159], %[" #WA "], off offset:400\n\t" \
  "s_waitcnt vmcnt(0)\n\t"

// P = prefetch dest reg (next step's A scalar), PC = consume reg
#define HALF(P, PC, R0,R1,R2,R3, WOFF) \
  "ds_read_b128 v[64:67], %[rb] offset:" #R0 "\n\t" \
  "ds_read_b128 v[68:71], %[rb] offset:" #R1 "\n\t" \
  "ds_read_b128 v[72:75], %[rb] offset:" #R2 "\n\t" \
  "ds_read_b128 v[76:79], %[rb] offset:" #R3 "\n\t" \
  "v_add_u32 v189, s80, %[at]\n\t" \
  "global_load_dword v" #P ", v189, %[ab]\n\t" \
  "s_add_u32 s80, s80, 2048\n\t" \
  "s_cmp_lg_u32 s80, 0x1000000\n\t" \
  "s_cselect_b32 s80, s80, 0\n\t" \
  /* mfma K-chunk-major, staggered waits: chunk k gated by read k only */ \
  "s_waitcnt lgkmcnt(3)\n\t" \
  "v_mfma_f32_16x16x32_f16 v[80:83], v[0:3],   v[64:67], v[164:167]\n\t" \
  "v_mfma_f32_16x16x32_f16 v[84:87], v[16:19], v[64:67], v[164:167]\n\t" \
  "v_mfma_f32_16x16x32_f16 v[88:91], v[32:35], v[64:67], v[164:167]\n\t" \
  "v_mfma_f32_16x16x32_f16 v[92:95], v[48:51], v[64:67], v[164:167]\n\t" \
  "s_waitcnt lgkmcnt(2)\n\t" \
  "v_mfma_f32_16x16x32_f16 v[80:83], v[4:7],   v[68:71], v[80:83]\n\t" \
  "v_mfma_f32_16x16x32_f16 v[84:87], v[20:23], v[68:71], v[84:87]\n\t" \
  "v_mfma_f32_16x16x32_f16 v[88:91], v[36:39], v[68:71], v[88:91]\n\t" \
  "v_mfma_f32_16x16x32_f16 v[92:95], v[52:55], v[68:71], v[92:95]\n\t" \
  "s_waitcnt lgkmcnt(1)\n\t" \
  "v_mfma_f32_16x16x32_f16 v[80:83], v[8:11],  v[72:75], v[80:83]\n\t" \
  "v_mfma_f32_16x16x32_f16 v[84:87], v[24:27], v[72:75], v[84:87]\n\t" \
  "v_mfma_f32_16x16x32_f16 v[88:91], v[40:43], v[72:75], v[88:91]\n\t" \
  "v_mfma_f32_16x16x32_f16 v[92:95], v[56:59], v[72:75], v[92:95]\n\t" \
  "s_waitcnt lgkmcnt(0)\n\t" \
  "v_mfma_f32_16x16x32_f16 v[80:83], v[12:15], v[76:79], v[80:83]\n\t" \
  "v_mfma_f32_16x16x32_f16 v[84:87], v[28:31], v[76:79], v[84:87]\n\t" \
  "v_mfma_f32_16x16x32_f16 v[88:91], v[44:47], v[76:79], v[88:91]\n\t" \
  "v_mfma_f32_16x16x32_f16 v[92:95], v[60:63], v[76:79], v[92:95]\n\t" \
  "s_nop 7\n\t" \
  /* D-select r = lane&3 per gate (i first: its result is oldest) */ \
  "v_cndmask_b32 v184, v80, v82, %[sb1]\n\t" \
  "v_cndmask_b32 v185, v81, v83, %[sb1]\n\t" \
  "v_cndmask_b32 v176, v184, v185, %[sb0]\n\t" \
  "v_cndmask_b32 v184, v84, v86, %[sb1]\n\t" \
  "v_cndmask_b32 v185, v85, v87, %[sb1]\n\t" \
  "v_cndmask_b32 v177, v184, v185, %[sb0]\n\t" \
  "v_cndmask_b32 v184, v88, v90, %[sb1]\n\t" \
  "v_cndmask_b32 v185, v89, v91, %[sb1]\n\t" \
  "v_cndmask_b32 v178, v184, v185, %[sb0]\n\t" \
  "v_cndmask_b32 v184, v92, v94, %[sb1]\n\t" \
  "v_cndmask_b32 v185, v93, v95, %[sb1]\n\t" \
  "v_cndmask_b32 v179, v184, v185, %[sb0]\n\t" \
  /* gate-select rr=(l>>2)&3: x = gate rr of u */ \
  "v_cndmask_b32 v180, v176, v177, %[sb2]\n\t" \
  "v_cndmask_b32 v181, v178, v179, %[sb2]\n\t" \
  "v_cndmask_b32 v182, v180, v181, %[sb3]\n\t" \
  /* + per-lane A bias (scalar, prefetched) */ \
  "s_waitcnt vmcnt(1)\n\t" \
  "v_add_f32 v182, v182, v" #PC "\n\t" \
  /* per-lane nonlin: y = rcp(1+exp2(m1*x))*sc + ad */ \
  "v_mul_f32 v183, %[m1], v182\n\t" \
  "v_exp_f32 v183, v183\n\t" \
  "s_nop 1\n\t" \
  "v_add_f32 v183, 1.0, v183\n\t" \
  "v_rcp_f32 v183, v183\n\t" \
  "s_nop 1\n\t" \
  "v_fma_f32 v183, v183, %[sc], %[ad]\n\t" \
  "s_nop 1\n\t" \
  /* gather quad gates. gfx950 row_ror:N delivers FROM lane (l-N)&15: */ \
  /* v184 (ror:4)  <- l+12 -> sigma_o ; v185 (ror:8) <- l+8 -> tanh g ; */ \
  /* v186 (ror:12) <- l+4  -> sigma_f   (in writer lanes rr=0)         */ \
  "v_mov_b32_dpp v184, v183 row_ror:4 row_mask:0xf bank_mask:0xf\n\t" \
  "v_mov_b32_dpp v185, v183 row_ror:8 row_mask:0xf bank_mask:0xf\n\t" \
  "v_mov_b32_dpp v186, v183 row_ror:12 row_mask:0xf bank_mask:0xf\n\t" \
  /* c = sf*c + si*tg  (valid in writer lanes; sf = v186) */ \
  "v_mul_f32 v187, v183, v185\n\t" \
  "v_fma_f32 v190, v186, v190, v187\n\t" \
  /* tanh(c) */ \
  "v_mul_f32 v188, s88, v190\n\t" \
  "v_exp_f32 v188, v188\n\t" \
  "s_nop 1\n\t" \
  "v_add_f32 v188, 1.0, v188\n\t" \
  "v_rcp_f32 v188, v188\n\t" \
  "s_nop 1\n\t" \
  "v_fma_f32 v188, v188, 2.0, -1.0\n\t" \
  "v_mul_f32 v188, v184, v188\n\t" \
  "v_cvt_f16_f32 v188, v188\n\t" \
  /* write h f16 (lanes with (l&12)==0) */ \
  "s_and_saveexec_b64 s[84:85], s[82:83]\n\t" \
  "ds_write_b16 %[wr], v188 offset:" #WOFF "\n\t" \
  "s_mov_b64 exec, s[84:85]\n\t" \
  "s_waitcnt lgkmcnt(0)\n\t" \
  "s_barrier\n\t"

__global__ __launch_bounds__(512, 2)
__attribute__((amdgpu_waves_per_eu(2, 2)))
void lstm_kernel(
    const float* __restrict__ A,      // (T,128,4)
    const float* __restrict__ W_hh,   // (512,128)
    const float* __restrict__ W_fc,   // (5,128)
    const float* __restrict__ b_fc,   // (5,)
    float* __restrict__ out)          // (5,)
{
    const int tid  = threadIdx.x;            // 0..511
    const int lane = tid & 63;
    const int wave = tid >> 6;               // 0..7
    const int q0   = wave * 16;              // first unit of this wave
    const int row  = lane & 15;              // A-fragment row
    const int kb8  = (lane >> 4) * 8;        // A/B fragment K-chunk base
    const int u    = q0 + 4 * (lane >> 4) + (lane & 3);  // this lane's unit
    const int rr   = (lane >> 2) & 3;        // redundancy group = own gate

    // h as f16: 2 buffers x 128 f16 = 512 B, linear layout
    __shared__ __align__(16) float h_s[2][64];

    if (tid < 128) ((float*)h_s)[tid] = 0.f;  // h_{-1} = 0 (both bufs)
    __syncthreads();

    // per-lane fragment addresses (row l&15, K base (l>>4)*8; kt via imm offs)
    const unsigned long long wai = (unsigned long long)(uintptr_t)(W_hh + (size_t)(q0 + row)        * D_LSTM + kb8);
    const unsigned long long waf = (unsigned long long)(uintptr_t)(W_hh + (size_t)(128 + q0 + row)  * D_LSTM + kb8);
    const unsigned long long wag = (unsigned long long)(uintptr_t)(W_hh + (size_t)(256 + q0 + row)  * D_LSTM + kb8);
    const unsigned long long wao = (unsigned long long)(uintptr_t)(W_hh + (size_t)(384 + q0 + row)  * D_LSTM + kb8);
    const unsigned int atid = (unsigned int)(u * 16 + rr * 4);   // A byte off (own gate scalar)
    const unsigned int lds0 = (unsigned int)(uintptr_t)&h_s[0][0];
    const unsigned int rb   = lds0 + (unsigned int)((lane >> 4) * 16);  // B-frag read base
    const unsigned int wr   = lds0 + (unsigned int)(u * 2);             // h write addr
    const unsigned long long wm  = __ballot((lane & 12) == 0);   // 16 writer lanes
    const unsigned long long sb0 = __ballot(lane & 1);
    const unsigned long long sb1 = __ballot(lane & 2);
    const unsigned long long sb2 = __ballot(lane & 4);
    const unsigned long long sb3 = __ballot(lane & 8);
    const float m1 = (rr == 2) ? -2.8853900817779268f  // -2*log2(e) -> tanh
                               : -1.4426950408889634f; // -log2(e)   -> sigmoid
    const float sc = (rr == 2) ? 2.0f : 1.0f;
    const float ad = (rr == 2) ? -1.0f : 0.0f;

    asm volatile(
        // ---- prologue: consts; pack weight fragments f32->f16 into v0-63 ----
        "s_mov_b32 s80, 2048\n\t"
        "s_mov_b32 s86, 4096\n\t"
        "s_mov_b32 s88, 0xC038AA3B\n\t"     // -2*log2(e)
        "s_mov_b64 s[82:83], %[wm]\n\t"
        FRAGLOAD(wai)
        ROWPACK(0,1,2,3,4,5,6,7,8,9,10,11,12,13,14,15)
        FRAGLOAD(waf)
        ROWPACK(16,17,18,19,20,21,22,23,24,25,26,27,28,29,30,31)
        FRAGLOAD(wag)
        ROWPACK(32,33,34,35,36,37,38,39,40,41,42,43,44,45,46,47)
        FRAGLOAD(wao)
        ROWPACK(48,49,50,51,52,53,54,55,56,57,58,59,60,61,62,63)
        // zero C operand + c state; load A row 0 (own-gate scalar)
        "v_mov_b32 v164, 0\n\t"
        "v_mov_b32 v165, 0\n\t"
        "v_mov_b32 v166, 0\n\t"
        "v_mov_b32 v167, 0\n\t"
        "global_load_dword v168, %[at], %[ab]\n\t"
        "s_waitcnt vmcnt(0)\n\t"
        "v_mov_b32 v190, 0\n\t"             // c = 0
        "1:\n\t"
        // even step: read buf0 (+0), consume v168, prefetch v172, write buf1 (+256)
        HALF(172, 168, 0,64,128,192, 256)
        // odd step: read buf1 (+256), consume v172, prefetch v168, write buf0 (+0)
        HALF(168, 172, 256,320,384,448, 0)
        "s_sub_u32 s86, s86, 1\n\t"
        "s_cmp_lg_u32 s86, 0\n\t"
        "s_cbranch_scc1 1b\n\t"
        :
        : [wai]"v"(wai), [waf]"v"(waf), [wag]"v"(wag), [wao]"v"(wao),
          [ab]"s"(A), [at]"v"(atid), [rb]"v"(rb), [wr]"v"(wr), [wm]"s"(wm),
          [sb0]"s"(sb0), [sb1]"s"(sb1), [sb2]"s"(sb2), [sb3]"s"(sb3),
          [m1]"v"(m1), [sc]"v"(sc), [ad]"v"(ad)
        : "v0","v1","v2","v3","v4","v5","v6","v7","v8","v9",
          "v10","v11","v12","v13","v14","v15","v16","v17","v18","v19",
          "v20","v21","v22","v23","v24","v25","v26","v27","v28","v29",
          "v30","v31","v32","v33","v34","v35","v36","v37","v38","v39",
          "v40","v41","v42","v43","v44","v45","v46","v47","v48","v49",
          "v50","v51","v52","v53","v54","v55","v56","v57","v58","v59",
          "v60","v61","v62","v63","v64","v65","v66","v67","v68","v69",
          "v70","v71","v72","v73","v74","v75","v76","v77","v78","v79",
          "v80","v81","v82","v83","v84","v85","v86","v87","v88","v89",
          "v90","v91","v92","v93","v94","v95","v96","v97","v98","v99",
          "v100","v101","v102","v103","v104","v105","v106","v107","v108","v109",
          "v110","v111","v112","v113","v114","v115","v116","v117","v118","v119",
          "v120","v121","v122","v123","v124","v125","v126","v127","v128","v129",
          "v130","v131","v132","v133","v134","v135","v136","v137","v138","v139",
          "v140","v141","v142","v143","v144","v145","v146","v147","v148","v149",
          "v150","v151","v152","v153","v154","v155","v156","v157","v158","v159",
          "v160","v161","v162","v163","v164","v165","v166","v167","v168","v169",
          "v170","v171","v172","v173","v174","v175","v176","v177","v178","v179",
          "v180","v181","v182","v183","v184","v185","v186","v187","v188","v189",
          "v190","v191",
          "s80","s81","s82","s83","s84","s85","s86","s87","s88",
          "scc","memory"
    );

    __syncthreads();

    // final FC: out = hT @ W_fc.T + b_fc  (final h in buffer 0, f16, linear)
    if (tid < N_CLS) {
        const __half* hh = (const __half*)&h_s[0][0];
        float acc = b_fc[tid];
        #pragma unroll
        for (int k = 0; k < D_LSTM; ++k) {
            acc += __half2float(hh[k]) * W_fc[tid * D_LSTM + k];
        }
        out[tid] = acc;
    }
}

// ---------------------------------------------------------------------------
extern "C" void kernel_launch(void* const* d_in, const int* in_sizes, int n_in,
                              void* d_out, int out_size, void* d_ws, size_t ws_size,
                              hipStream_t stream) {
    const float* x       = (const float*)d_in[0];
    const int*   esrc    = (const int*)  d_in[1];
    const int*   edst    = (const int*)  d_in[2];
    const float* W_rel1  = (const float*)d_in[3];
    const float* b_rel1  = (const float*)d_in[4];
    const float* W_root1 = (const float*)d_in[5];
    const float* W_rel2  = (const float*)d_in[6];
    const float* b_rel2  = (const float*)d_in[7];
    const float* W_root2 = (const float*)d_in[8];
    const float* W_ih    = (const float*)d_in[9];
    const float* W_hh    = (const float*)d_in[10];
    const float* b_ih    = (const float*)d_in[11];
    const float* b_hh    = (const float*)d_in[12];
    const float* W_fc    = (const float*)d_in[13];
    const float* b_fc    = (const float*)d_in[14];

    float* out = (float*)d_out;
    float* A   = (float*)d_ws;   // (T,128,4) f32 = 16 MB

    gnn_proj_kernel<<<T_LEN / TB, 64, 0, stream>>>(
        x, esrc, edst, W_rel1, b_rel1, W_root1,
        W_rel2, b_rel2, W_root2, W_ih, b_ih, b_hh, A);

    lstm_kernel<<<1, 512, 0, stream>>>(A, W_hh, W_fc, b_fc, out);
}